// Round 5
// baseline (1497.161 us; speedup 1.0000x reference)
//
#include <hip/hip_runtime.h>

#define Nn 100000
#define Ee 600000
#define Hh 128
#define NP 100096  // padded node rows: multiple of 64
#define NT (NP / 64)  // 1564 tiles

typedef short bf16x8 __attribute__((ext_vector_type(8)));
typedef float f32x4 __attribute__((ext_vector_type(4)));
typedef unsigned short u16x8 __attribute__((ext_vector_type(8)));

static __device__ __forceinline__ float sigmoidf_(float x) {
  return 1.0f / (1.0f + __expf(-x));
}
static __device__ __forceinline__ float tanh_fast(float x) {
  return 1.0f - 2.0f / (__expf(2.0f * x) + 1.0f);
}
// round-to-nearest-even fp32 -> bf16 bits
static __device__ __forceinline__ ushort f2bf(float v) {
  unsigned u = __float_as_uint(v);
  unsigned r = (u + 0x7fffu + ((u >> 16) & 1u)) >> 16;
  return (ushort)r;
}
static __device__ __forceinline__ float bf2f(ushort b) {
  return __uint_as_float(((unsigned)b) << 16);
}
static __device__ __forceinline__ f32x4 max4(f32x4 a, f32x4 b) {
  f32x4 r;
  r[0] = fmaxf(a[0], b[0]);
  r[1] = fmaxf(a[1], b[1]);
  r[2] = fmaxf(a[2], b[2]);
  r[3] = fmaxf(a[3], b[3]);
  return r;
}
// H fragment-major fp32 layout: [tile][kc:4][rf:4][g:4][c16:16][j:8]
// element (row r, dim d): tile=r>>6, rf=(r>>4)&3, c16=r&15; kc=d>>5, g=(d>>3)&3, j=d&7

__global__ void zero_kernel(int* __restrict__ a, int* __restrict__ b, int n) {
  int i = blockIdx.x * 256 + threadIdx.x;
  if (i < n) { a[i] = 0; b[i] = 0; }
}

__global__ void count_kernel(const int* __restrict__ ei, int* __restrict__ degi,
                             int* __restrict__ cnt) {
  int e = blockIdx.x * 256 + threadIdx.x;
  if (e >= Ee) return;
  int r = ei[e], c = ei[Ee + e];
  atomicAdd(&degi[r], 1);
  atomicAdd(&degi[c], 1);
  atomicAdd(&cnt[c], 1);
}

__global__ void dis_kernel(const int* __restrict__ degi, float* __restrict__ dis) {
  int i = blockIdx.x * 256 + threadIdx.x;
  if (i < Nn) dis[i] = rsqrtf((float)degi[i] + 1.0f);
}

__global__ void scan_partial(const int* __restrict__ cnt, int* __restrict__ bsum) {
  __shared__ int s[256];
  int i = blockIdx.x * 256 + threadIdx.x;
  s[threadIdx.x] = (i < Nn) ? cnt[i] : 0;
  __syncthreads();
  for (int off = 128; off > 0; off >>= 1) {
    if (threadIdx.x < off) s[threadIdx.x] += s[threadIdx.x + off];
    __syncthreads();
  }
  if (threadIdx.x == 0) bsum[blockIdx.x] = s[0];
}

__global__ void scan_bsums(const int* __restrict__ bsum, int* __restrict__ bpre, int nb) {
  __shared__ int s[512];
  int t = threadIdx.x;
  s[t] = (t < nb) ? bsum[t] : 0;
  __syncthreads();
  for (int off = 1; off < 512; off <<= 1) {
    int u = (t >= off) ? s[t - off] : 0;
    __syncthreads();
    s[t] += u;
    __syncthreads();
  }
  if (t < nb) bpre[t] = (t == 0) ? 0 : s[t - 1];
}

__global__ void scan_final(const int* __restrict__ cnt, const int* __restrict__ bpre,
                           int* __restrict__ rowptr, int* __restrict__ cursor) {
  __shared__ int s[256];
  int t = threadIdx.x;
  int i = blockIdx.x * 256 + t;
  int v = (i < Nn) ? cnt[i] : 0;
  s[t] = v;
  __syncthreads();
  for (int off = 1; off < 256; off <<= 1) {
    int u = (t >= off) ? s[t - off] : 0;
    __syncthreads();
    s[t] += u;
    __syncthreads();
  }
  int excl = s[t] - v;
  int base = bpre[blockIdx.x];
  if (i < Nn) { rowptr[i] = base + excl; cursor[i] = base + excl; }
  if (i == Nn - 1) rowptr[Nn] = base + excl + v;
}

__global__ void fill_kernel(const int* __restrict__ ei, const float* __restrict__ dis,
                            int* __restrict__ cursor, int* __restrict__ csr_src,
                            float* __restrict__ csr_w) {
  int e = blockIdx.x * 256 + threadIdx.x;
  if (e >= Ee) return;
  int r = ei[e], c = ei[Ee + e];
  int p = atomicAdd(&cursor[c], 1);
  csr_src[p] = r;
  csr_w[p] = dis[r] * dis[c];
}

// Pack GRU weights into fragment-major split-bf16:
// B[kc:8][fid:24][g][c16][j], fid = gate*8+f; k = kc*32+g*8+j, col c=(fid&7)*16+c16,
// weight row = gate*128 + c. kc<4 -> Wih, kc>=4 -> Whh.
__global__ void pack_kernel(const float* __restrict__ Wih, const float* __restrict__ Whh,
                            ushort* __restrict__ Bhi, ushort* __restrict__ Blo) {
  int t = blockIdx.x * 256 + threadIdx.x;  // 8*24*4*16 = 12288 threads
  if (t >= 8 * 24 * 4 * 16) return;
  int c16 = t & 15;
  int g = (t >> 4) & 3;
  int fid = (t >> 6) % 24;
  int kc = t / (24 * 64);
  int gate = fid >> 3, f = fid & 7;
  int c = f * 16 + c16;
  int wrow = gate * 128 + c;
  size_t base = (size_t)t * 8;
#pragma unroll
  for (int j = 0; j < 8; ++j) {
    int k = kc * 32 + g * 8 + j;
    float v = (k < 128) ? Wih[wrow * 128 + k] : Whh[wrow * 128 + (k - 128)];
    ushort hi = f2bf(v);
    Bhi[base + j] = hi;
    Blo[base + j] = f2bf(v - bf2f(hi));
  }
}

// Pack MLP W1 (64 x 128): Bm[kc][cf][g][c16][j], c = cf*16+c16, k = kc*32+g*8+j
__global__ void pack_mlp(const float* __restrict__ Wm1, ushort* __restrict__ Bh,
                         ushort* __restrict__ Bl) {
  int t = blockIdx.x * 256 + threadIdx.x;  // 4*4*4*16 = 1024
  if (t >= 1024) return;
  int c16 = t & 15;
  int g = (t >> 4) & 3;
  int cf = (t >> 6) & 3;
  int kc = t >> 8;
  int c = cf * 16 + c16;
  size_t base = (size_t)t * 8;
#pragma unroll
  for (int j = 0; j < 8; ++j) {
    int k = kc * 32 + g * 8 + j;
    float v = Wm1[c * 128 + k];
    ushort hi = f2bf(v);
    Bh[base + j] = hi;
    Bl[base + j] = f2bf(v - bf2f(hi));
  }
}

// h0: leaky_relu(X @ W0^T + b0) written into H0 fragment-major fp32.
__global__ void h0_kernel(const float* __restrict__ X, const float* __restrict__ W0,
                          const float* __restrict__ b0, float* __restrict__ H0) {
  int t = blockIdx.x * 256 + threadIdx.x;
  int i = t >> 7, d = t & 127;
  if (i >= NP) return;
  float v = 0.0f;
  if (i < Nn) {
    float x0 = X[i * 3 + 0], x1 = X[i * 3 + 1], x2 = X[i * 3 + 2];
    v = fmaf(x0, W0[d * 3 + 0], fmaf(x1, W0[d * 3 + 1], fmaf(x2, W0[d * 3 + 2], b0[d])));
    v = v > 0.0f ? v : 0.01f * v;
  }
  size_t off = (size_t)(i >> 6) * 8192 + (size_t)(d >> 5) * 2048 +
               (size_t)((i >> 4) & 3) * 512 + (size_t)((d >> 3) & 3) * 128 +
               (size_t)(i & 15) * 8 + (d & 7);
  H0[off] = v;
}

// ---- Fused GCN-aggregate + GRU cell ----
// Block = 64 nodes (one tile), 256 threads = 4 waves.
// Phase 1: gather (4 threads/node, 32 dims each) -> split-bf16 fragments in LDS.
// Phase 2: MFMA over kc 0..3 (LDS agg) and kc 4..7 (global H_prev, split on the fly).
// Phase 3: gate epilogue, write H_new (fp32 fragment-major).

#define DO_GATE(GB, ACC)                                                              \
  {                                                                                   \
    bf16x8 bH[2], bL[2];                                                              \
    _Pragma("unroll") for (int cf = 0; cf < 2; ++cf) {                                \
      size_t boff = (((size_t)(kc * 24 + (GB)*8 + wave * 2 + cf) * 4 + g) * 16 + c16) * 8; \
      bH[cf] = *(const bf16x8*)(Bhi + boff);                                          \
      bL[cf] = *(const bf16x8*)(Blo + boff);                                          \
    }                                                                                 \
    _Pragma("unroll") for (int cf = 0; cf < 2; ++cf)                                  \
        _Pragma("unroll") for (int rf = 0; rf < 4; ++rf)                              \
            ACC[rf][cf] = __builtin_amdgcn_mfma_f32_16x16x32_bf16(aH[rf], bH[cf], ACC[rf][cf], 0, 0, 0); \
    _Pragma("unroll") for (int cf = 0; cf < 2; ++cf)                                  \
        _Pragma("unroll") for (int rf = 0; rf < 4; ++rf)                              \
            ACC[rf][cf] = __builtin_amdgcn_mfma_f32_16x16x32_bf16(aH[rf], bL[cf], ACC[rf][cf], 0, 0, 0); \
    _Pragma("unroll") for (int cf = 0; cf < 2; ++cf)                                  \
        _Pragma("unroll") for (int rf = 0; rf < 4; ++rf)                              \
            ACC[rf][cf] = __builtin_amdgcn_mfma_f32_16x16x32_bf16(aL[rf], bH[cf], ACC[rf][cf], 0, 0, 0); \
  }

__global__ __launch_bounds__(256, 2) void gcn_gru_fused(
    const float* __restrict__ Hp, float* __restrict__ Hn,
    const int* __restrict__ csr_src, const float* __restrict__ csr_w,
    const int* __restrict__ rowptr,
    const ushort* __restrict__ Bhi, const ushort* __restrict__ Blo,
    const float* __restrict__ bih, const float* __restrict__ bhh) {
  __shared__ ushort AsH[8192];
  __shared__ ushort AsL[8192];
  const int tid = threadIdx.x;
  const int tile = blockIdx.x;
  const long rowbase = (long)tile * 64;

  // ---- Phase 1: gather ----
  {
    const int local = tid >> 2;  // 0..63
    const int kc = tid & 3;      // dim block: d = kc*32 + 0..31
    const long node = rowbase + local;
    float acc[32];
#pragma unroll
    for (int m = 0; m < 32; ++m) acc[m] = 0.0f;
    if (node < Nn) {
      const int e0 = rowptr[node], e1 = rowptr[node + 1];
      for (int e = e0; e < e1; ++e) {
        const int src = csr_src[e];
        const float w = csr_w[e];
        const float* p = Hp + ((size_t)(src >> 6) * 8192 + (size_t)kc * 2048 +
                               (size_t)((src >> 4) & 3) * 512 + (size_t)(src & 15) * 8);
#pragma unroll
        for (int g2 = 0; g2 < 4; ++g2) {
          f32x4 v0 = *(const f32x4*)(p + g2 * 128);
          f32x4 v1 = *(const f32x4*)(p + g2 * 128 + 4);
#pragma unroll
          for (int m = 0; m < 4; ++m) {
            acc[g2 * 8 + m] = fmaf(w, v0[m], acc[g2 * 8 + m]);
            acc[g2 * 8 + 4 + m] = fmaf(w, v1[m], acc[g2 * 8 + 4 + m]);
          }
        }
      }
    }
    const int rf = local >> 4, c16l = local & 15;
#pragma unroll
    for (int g2 = 0; g2 < 4; ++g2) {
      u16x8 vh, vl;
#pragma unroll
      for (int j = 0; j < 8; ++j) {
        float v = acc[g2 * 8 + j];
        ushort hb = f2bf(v);
        vh[j] = hb;
        vl[j] = f2bf(v - bf2f(hb));
      }
      int off = kc * 2048 + rf * 512 + g2 * 128 + c16l * 8;
      *(u16x8*)(AsH + off) = vh;
      *(u16x8*)(AsL + off) = vl;
    }
  }
  __syncthreads();

  // ---- Phase 2: MFMA ----
  const int wave = tid >> 6, lane = tid & 63;
  const int g = lane >> 4, c16 = lane & 15;
  const int lbase = g * 128 + c16 * 8;
  const size_t gbase = (size_t)tile * 8192 + lbase;

  f32x4 accR[4][2], accZ[4][2], accXN[4][2], accHN[4][2];
#pragma unroll
  for (int rf = 0; rf < 4; ++rf)
#pragma unroll
    for (int cf = 0; cf < 2; ++cf) {
      accR[rf][cf] = (f32x4){0.f, 0.f, 0.f, 0.f};
      accZ[rf][cf] = (f32x4){0.f, 0.f, 0.f, 0.f};
      accXN[rf][cf] = (f32x4){0.f, 0.f, 0.f, 0.f};
      accHN[rf][cf] = (f32x4){0.f, 0.f, 0.f, 0.f};
    }

#pragma unroll
  for (int kc = 0; kc < 4; ++kc) {
    bf16x8 aH[4], aL[4];
#pragma unroll
    for (int rf = 0; rf < 4; ++rf) {
      int off = kc * 2048 + rf * 512 + lbase;
      aH[rf] = *(const bf16x8*)(AsH + off);
      aL[rf] = *(const bf16x8*)(AsL + off);
    }
    DO_GATE(0, accR)
    DO_GATE(1, accZ)
    DO_GATE(2, accXN)
  }
#pragma unroll
  for (int kc = 4; kc < 8; ++kc) {
    bf16x8 aH[4], aL[4];
#pragma unroll
    for (int rf = 0; rf < 4; ++rf) {
      const float* p = Hp + gbase + (size_t)(kc - 4) * 2048 + (size_t)rf * 512;
      f32x4 v0 = *(const f32x4*)p;
      f32x4 v1 = *(const f32x4*)(p + 4);
      u16x8 vh, vl;
#pragma unroll
      for (int m = 0; m < 4; ++m) {
        ushort hb0 = f2bf(v0[m]);
        vh[m] = hb0;
        vl[m] = f2bf(v0[m] - bf2f(hb0));
        ushort hb1 = f2bf(v1[m]);
        vh[4 + m] = hb1;
        vl[4 + m] = f2bf(v1[m] - bf2f(hb1));
      }
      aH[rf] = (bf16x8)vh;
      aL[rf] = (bf16x8)vl;
    }
    DO_GATE(0, accR)
    DO_GATE(1, accZ)
    DO_GATE(2, accHN)
  }

  // ---- Phase 3: epilogue ----
#pragma unroll
  for (int cf = 0; cf < 2; ++cf) {
    const int c = (wave * 2 + cf) * 16 + c16;
    const float br = bih[c] + bhh[c];
    const float bz = bih[128 + c] + bhh[128 + c];
    const float bxn = bih[256 + c];
    const float bhn = bhh[256 + c];
    const int g2 = (2 * cf + (c16 >> 3)) & 3;
    const int j2 = c16 & 7;
#pragma unroll
    for (int rf = 0; rf < 4; ++rf) {
#pragma unroll
      for (int reg = 0; reg < 4; ++reg) {
        size_t off = (size_t)tile * 8192 + (size_t)wave * 2048 + (size_t)rf * 512 +
                     (size_t)g2 * 128 + (size_t)(g * 4 + reg) * 8 + j2;
        float hold = Hp[off];
        float rr = sigmoidf_(accR[rf][cf][reg] + br);
        float zz = sigmoidf_(accZ[rf][cf][reg] + bz);
        float nn = tanh_fast(accXN[rf][cf][reg] + bxn + rr * (accHN[rf][cf][reg] + bhn));
        Hn[off] = (1.0f - zz) * nn + zz * hold;
      }
    }
  }
}

// ---- Fused max(h1..h5) + MLP ----
// Block = 64 nodes, 4 waves; wave w owns cols [16w, 16w+16) of hid (64 cols).
__global__ __launch_bounds__(256, 2) void mlp_max_mfma(
    const float* __restrict__ H1, const float* __restrict__ H2,
    const float* __restrict__ H3, const float* __restrict__ H4,
    const float* __restrict__ H5,
    const ushort* __restrict__ Bh, const ushort* __restrict__ Bl,
    const float* __restrict__ bm1, const float* __restrict__ Wm2,
    const float* __restrict__ bm2, float* __restrict__ out) {
  __shared__ float red[4][64];
  const int tid = threadIdx.x;
  const int wave = tid >> 6, lane = tid & 63;
  const int g = lane >> 4, c16 = lane & 15;
  const long rowbase = (long)blockIdx.x * 64;
  const size_t gbase = (size_t)blockIdx.x * 8192 + (size_t)g * 128 + (size_t)c16 * 8;

  f32x4 acc[4];
#pragma unroll
  for (int rf = 0; rf < 4; ++rf) acc[rf] = (f32x4){0.f, 0.f, 0.f, 0.f};

#pragma unroll
  for (int kc = 0; kc < 4; ++kc) {
    bf16x8 aH[4], aL[4];
#pragma unroll
    for (int rf = 0; rf < 4; ++rf) {
      size_t o = gbase + (size_t)kc * 2048 + (size_t)rf * 512;
      f32x4 m0 = *(const f32x4*)(H1 + o);
      f32x4 m1 = *(const f32x4*)(H1 + o + 4);
      m0 = max4(m0, *(const f32x4*)(H2 + o));
      m1 = max4(m1, *(const f32x4*)(H2 + o + 4));
      m0 = max4(m0, *(const f32x4*)(H3 + o));
      m1 = max4(m1, *(const f32x4*)(H3 + o + 4));
      m0 = max4(m0, *(const f32x4*)(H4 + o));
      m1 = max4(m1, *(const f32x4*)(H4 + o + 4));
      m0 = max4(m0, *(const f32x4*)(H5 + o));
      m1 = max4(m1, *(const f32x4*)(H5 + o + 4));
      u16x8 vh, vl;
#pragma unroll
      for (int m = 0; m < 4; ++m) {
        ushort hb0 = f2bf(m0[m]);
        vh[m] = hb0;
        vl[m] = f2bf(m0[m] - bf2f(hb0));
        ushort hb1 = f2bf(m1[m]);
        vh[4 + m] = hb1;
        vl[4 + m] = f2bf(m1[m] - bf2f(hb1));
      }
      aH[rf] = (bf16x8)vh;
      aL[rf] = (bf16x8)vl;
    }
    size_t boff = (((size_t)(kc * 4 + wave) * 4 + g) * 16 + c16) * 8;
    bf16x8 bH = *(const bf16x8*)(Bh + boff);
    bf16x8 bL = *(const bf16x8*)(Bl + boff);
#pragma unroll
    for (int rf = 0; rf < 4; ++rf)
      acc[rf] = __builtin_amdgcn_mfma_f32_16x16x32_bf16(aH[rf], bH, acc[rf], 0, 0, 0);
#pragma unroll
    for (int rf = 0; rf < 4; ++rf)
      acc[rf] = __builtin_amdgcn_mfma_f32_16x16x32_bf16(aH[rf], bL, acc[rf], 0, 0, 0);
#pragma unroll
    for (int rf = 0; rf < 4; ++rf)
      acc[rf] = __builtin_amdgcn_mfma_f32_16x16x32_bf16(aL[rf], bH, acc[rf], 0, 0, 0);
  }

  const int c = wave * 16 + c16;
  const float b1 = bm1[c];
  const float w2 = Wm2[c];
#pragma unroll
  for (int rf = 0; rf < 4; ++rf) {
#pragma unroll
    for (int reg = 0; reg < 4; ++reg) {
      float v = acc[rf][reg] + b1;
      v = v > 0.f ? v : 0.01f * v;
      v *= w2;
#pragma unroll
      for (int off = 1; off < 16; off <<= 1) v += __shfl_xor(v, off);
      if (c16 == 0) red[wave][rf * 16 + g * 4 + reg] = v;
    }
  }
  __syncthreads();
  if (tid < 64) {
    long row = rowbase + tid;
    if (row < Nn)
      out[row] = red[0][tid] + red[1][tid] + red[2][tid] + red[3][tid] + bm2[0];
  }
}

extern "C" void kernel_launch(void* const* d_in, const int* in_sizes, int n_in,
                              void* d_out, int out_size, void* d_ws, size_t ws_size,
                              hipStream_t stream) {
  const float* X = (const float*)d_in[0];
  const int* ei = (const int*)d_in[1];
  const float* W0 = (const float*)d_in[2];
  const float* b0 = (const float*)d_in[3];
  const float* Wih = (const float*)d_in[4];
  const float* Whh = (const float*)d_in[5];
  const float* bih = (const float*)d_in[6];
  const float* bhh = (const float*)d_in[7];
  const float* Wm1 = (const float*)d_in[8];
  const float* bm1 = (const float*)d_in[9];
  const float* Wm2 = (const float*)d_in[10];
  const float* bm2 = (const float*)d_in[11];
  float* out = (float*)d_out;

  char* ws = (char*)d_ws;
  size_t off = 0;
  auto alloc = [&](size_t bytes) -> void* {
    void* p = ws + off;
    off = (off + bytes + 255) & ~(size_t)255;
    return p;
  };
  float* Hs[5];
  for (int i = 0; i < 5; ++i) Hs[i] = (float*)alloc((size_t)NT * 8192 * 4);
  ushort* Bhi = (ushort*)alloc((size_t)8 * 24 * 4 * 16 * 8 * 2);
  ushort* Blo = (ushort*)alloc((size_t)8 * 24 * 4 * 16 * 8 * 2);
  ushort* Bmh = (ushort*)alloc((size_t)1024 * 8 * 2);
  ushort* Bml = (ushort*)alloc((size_t)1024 * 8 * 2);
  float* dis = (float*)alloc((size_t)Nn * 4);
  int* degi = (int*)alloc((size_t)Nn * 4);
  int* cnt = (int*)alloc((size_t)Nn * 4);
  int* rowptr = (int*)alloc((size_t)(Nn + 1) * 4);
  int* cursor = (int*)alloc((size_t)Nn * 4);
  int* bsum = (int*)alloc(512 * 4);
  int* bpre = (int*)alloc(512 * 4);
  int* csr_src = (int*)alloc((size_t)Ee * 4);
  float* csr_w = (float*)alloc((size_t)Ee * 4);
  (void)ws_size;
  (void)in_sizes;
  (void)n_in;
  (void)out_size;

  const int NB = (Nn + 255) / 256;  // 391
  const int EB = (Ee + 255) / 256;  // 2344

  zero_kernel<<<NB, 256, 0, stream>>>(degi, cnt, Nn);
  count_kernel<<<EB, 256, 0, stream>>>(ei, degi, cnt);
  dis_kernel<<<NB, 256, 0, stream>>>(degi, dis);
  scan_partial<<<NB, 256, 0, stream>>>(cnt, bsum);
  scan_bsums<<<1, 512, 0, stream>>>(bsum, bpre, NB);
  scan_final<<<NB, 256, 0, stream>>>(cnt, bpre, rowptr, cursor);
  fill_kernel<<<EB, 256, 0, stream>>>(ei, dis, cursor, csr_src, csr_w);
  pack_kernel<<<48, 256, 0, stream>>>(Wih, Whh, Bhi, Blo);
  pack_mlp<<<4, 256, 0, stream>>>(Wm1, Bmh, Bml);
  h0_kernel<<<(NP * Hh) / 256, 256, 0, stream>>>(X, W0, b0, Hs[0]);

  // iteration t: read Hs[(t-1)%5], write Hs[t%5]  (t=5 reuses slot 0; h0 is dead by then)
  for (int t = 1; t <= 5; ++t) {
    gcn_gru_fused<<<NT, 256, 0, stream>>>(Hs[(t - 1) % 5], Hs[t % 5], csr_src, csr_w,
                                          rowptr, Bhi, Blo, bih, bhh);
  }

  mlp_max_mfma<<<NT, 256, 0, stream>>>(Hs[1], Hs[2], Hs[3], Hs[4], Hs[0], Bmh, Bml,
                                       bm1, Wm2, bm2, out);
}

// Round 6
// 938.862 us; speedup vs baseline: 1.5947x; 1.5947x over previous
//
#include <hip/hip_runtime.h>

#define Nn 100000
#define Ee 600000
#define Hh 128
#define NP 100096  // padded node rows: multiple of 64
#define NT (NP / 64)  // 1564 tiles

typedef short bf16x8 __attribute__((ext_vector_type(8)));
typedef float f32x4 __attribute__((ext_vector_type(4)));
typedef unsigned short u16x8 __attribute__((ext_vector_type(8)));

static __device__ __forceinline__ float sigmoidf_(float x) {
  return 1.0f / (1.0f + __expf(-x));
}
static __device__ __forceinline__ float tanh_fast(float x) {
  return 1.0f - 2.0f / (__expf(2.0f * x) + 1.0f);
}
// round-to-nearest-even fp32 -> bf16 bits
static __device__ __forceinline__ ushort f2bf(float v) {
  unsigned u = __float_as_uint(v);
  unsigned r = (u + 0x7fffu + ((u >> 16) & 1u)) >> 16;
  return (ushort)r;
}
static __device__ __forceinline__ float bf2f(ushort b) {
  return __uint_as_float(((unsigned)b) << 16);
}
static __device__ __forceinline__ f32x4 max4(f32x4 a, f32x4 b) {
  f32x4 r;
  r[0] = fmaxf(a[0], b[0]);
  r[1] = fmaxf(a[1], b[1]);
  r[2] = fmaxf(a[2], b[2]);
  r[3] = fmaxf(a[3], b[3]);
  return r;
}
// LDS fragment layout (ushort idx): [kc:4][rf:4][g:4][c16:16][j:8]
// element (local row r, dim d): rf=r>>4, c16=r&15; kc=d>>5, g=(d>>3)&3, j=d&7

__global__ void zero_kernel(int* __restrict__ a, int* __restrict__ b, int n) {
  int i = blockIdx.x * 256 + threadIdx.x;
  if (i < n) { a[i] = 0; b[i] = 0; }
}

__global__ void count_kernel(const int* __restrict__ ei, int* __restrict__ degi,
                             int* __restrict__ cnt) {
  int e = blockIdx.x * 256 + threadIdx.x;
  if (e >= Ee) return;
  int r = ei[e], c = ei[Ee + e];
  atomicAdd(&degi[r], 1);
  atomicAdd(&degi[c], 1);
  atomicAdd(&cnt[c], 1);
}

__global__ void dis_kernel(const int* __restrict__ degi, float* __restrict__ dis) {
  int i = blockIdx.x * 256 + threadIdx.x;
  if (i < Nn) dis[i] = rsqrtf((float)degi[i] + 1.0f);
}

__global__ void scan_partial(const int* __restrict__ cnt, int* __restrict__ bsum) {
  __shared__ int s[256];
  int i = blockIdx.x * 256 + threadIdx.x;
  s[threadIdx.x] = (i < Nn) ? cnt[i] : 0;
  __syncthreads();
  for (int off = 128; off > 0; off >>= 1) {
    if (threadIdx.x < off) s[threadIdx.x] += s[threadIdx.x + off];
    __syncthreads();
  }
  if (threadIdx.x == 0) bsum[blockIdx.x] = s[0];
}

__global__ void scan_bsums(const int* __restrict__ bsum, int* __restrict__ bpre, int nb) {
  __shared__ int s[512];
  int t = threadIdx.x;
  s[t] = (t < nb) ? bsum[t] : 0;
  __syncthreads();
  for (int off = 1; off < 512; off <<= 1) {
    int u = (t >= off) ? s[t - off] : 0;
    __syncthreads();
    s[t] += u;
    __syncthreads();
  }
  if (t < nb) bpre[t] = (t == 0) ? 0 : s[t - 1];
}

__global__ void scan_final(const int* __restrict__ cnt, const int* __restrict__ bpre,
                           int* __restrict__ rowptr, int* __restrict__ cursor) {
  __shared__ int s[256];
  int t = threadIdx.x;
  int i = blockIdx.x * 256 + t;
  int v = (i < Nn) ? cnt[i] : 0;
  s[t] = v;
  __syncthreads();
  for (int off = 1; off < 256; off <<= 1) {
    int u = (t >= off) ? s[t - off] : 0;
    __syncthreads();
    s[t] += u;
    __syncthreads();
  }
  int excl = s[t] - v;
  int base = bpre[blockIdx.x];
  if (i < Nn) { rowptr[i] = base + excl; cursor[i] = base + excl; }
  if (i == Nn - 1) rowptr[Nn] = base + excl + v;
}

__global__ void fill_kernel(const int* __restrict__ ei, const float* __restrict__ dis,
                            int* __restrict__ cursor, int* __restrict__ csr_src,
                            float* __restrict__ csr_w) {
  int e = blockIdx.x * 256 + threadIdx.x;
  if (e >= Ee) return;
  int r = ei[e], c = ei[Ee + e];
  int p = atomicAdd(&cursor[c], 1);
  csr_src[p] = r;
  csr_w[p] = dis[r] * dis[c];
}

// Pack GRU weights into fragment-major split-bf16:
// B[kc:8][fid:24][g][c16][j], fid = gate*8+f; k = kc*32+g*8+j, col c=(fid&7)*16+c16,
// weight row = gate*128 + c. kc<4 -> Wih, kc>=4 -> Whh.
__global__ void pack_kernel(const float* __restrict__ Wih, const float* __restrict__ Whh,
                            ushort* __restrict__ Bhi, ushort* __restrict__ Blo) {
  int t = blockIdx.x * 256 + threadIdx.x;  // 8*24*4*16 = 12288 threads
  if (t >= 8 * 24 * 4 * 16) return;
  int c16 = t & 15;
  int g = (t >> 4) & 3;
  int fid = (t >> 6) % 24;
  int kc = t / (24 * 64);
  int gate = fid >> 3, f = fid & 7;
  int c = f * 16 + c16;
  int wrow = gate * 128 + c;
  size_t base = (size_t)t * 8;
#pragma unroll
  for (int j = 0; j < 8; ++j) {
    int k = kc * 32 + g * 8 + j;
    float v = (k < 128) ? Wih[wrow * 128 + k] : Whh[wrow * 128 + (k - 128)];
    ushort hi = f2bf(v);
    Bhi[base + j] = hi;
    Blo[base + j] = f2bf(v - bf2f(hi));
  }
}

// Pack MLP W1 (64 x 128): Bm[kc][cf][g][c16][j], c = cf*16+c16, k = kc*32+g*8+j
__global__ void pack_mlp(const float* __restrict__ Wm1, ushort* __restrict__ Bh,
                         ushort* __restrict__ Bl) {
  int t = blockIdx.x * 256 + threadIdx.x;  // 4*4*4*16 = 1024
  if (t >= 1024) return;
  int c16 = t & 15;
  int g = (t >> 4) & 3;
  int cf = (t >> 6) & 3;
  int kc = t >> 8;
  int c = cf * 16 + c16;
  size_t base = (size_t)t * 8;
#pragma unroll
  for (int j = 0; j < 8; ++j) {
    int k = kc * 32 + g * 8 + j;
    float v = Wm1[c * 128 + k];
    ushort hi = f2bf(v);
    Bh[base + j] = hi;
    Bl[base + j] = f2bf(v - bf2f(hi));
  }
}

// h0: leaky_relu(X @ W0^T + b0), row-major fp32.
__global__ void h0_kernel(const float* __restrict__ X, const float* __restrict__ W0,
                          const float* __restrict__ b0, float* __restrict__ H0) {
  int t = blockIdx.x * 256 + threadIdx.x;
  int i = t >> 7, d = t & 127;
  if (i >= NP) return;
  float v = 0.0f;
  if (i < Nn) {
    float x0 = X[i * 3 + 0], x1 = X[i * 3 + 1], x2 = X[i * 3 + 2];
    v = fmaf(x0, W0[d * 3 + 0], fmaf(x1, W0[d * 3 + 1], fmaf(x2, W0[d * 3 + 2], b0[d])));
    v = v > 0.0f ? v : 0.01f * v;
  }
  H0[(size_t)i * Hh + d] = v;
}

// ---- Fused GCN-aggregate + GRU cell (row-major fp32 state) ----
// Block = 64 nodes (one tile), 256 threads = 4 waves. LDS 64KB.
// Phase 0: stage own 64 rows -> split-bf16 fragments HsH/HsL.
// Phase 1: gather (4 thr/node x 32 contiguous dims) -> split-bf16 AsH/AsL.
// Phase 2: MFMA (kc0..3 from As, kc4..7 from Hs).
// Phase 3: gate epilogue; hold from Hs (hi+lo); write Hn row-major.

#define DO_GATE(GB, ACC)                                                              \
  {                                                                                   \
    bf16x8 bH[2], bL[2];                                                              \
    _Pragma("unroll") for (int cf = 0; cf < 2; ++cf) {                                \
      size_t boff = (((size_t)(kc * 24 + (GB)*8 + wave * 2 + cf) * 4 + g) * 16 + c16) * 8; \
      bH[cf] = *(const bf16x8*)(Bhi + boff);                                          \
      bL[cf] = *(const bf16x8*)(Blo + boff);                                          \
    }                                                                                 \
    _Pragma("unroll") for (int cf = 0; cf < 2; ++cf)                                  \
        _Pragma("unroll") for (int rf = 0; rf < 4; ++rf)                              \
            ACC[rf][cf] = __builtin_amdgcn_mfma_f32_16x16x32_bf16(aH[rf], bH[cf], ACC[rf][cf], 0, 0, 0); \
    _Pragma("unroll") for (int cf = 0; cf < 2; ++cf)                                  \
        _Pragma("unroll") for (int rf = 0; rf < 4; ++rf)                              \
            ACC[rf][cf] = __builtin_amdgcn_mfma_f32_16x16x32_bf16(aH[rf], bL[cf], ACC[rf][cf], 0, 0, 0); \
    _Pragma("unroll") for (int cf = 0; cf < 2; ++cf)                                  \
        _Pragma("unroll") for (int rf = 0; rf < 4; ++rf)                              \
            ACC[rf][cf] = __builtin_amdgcn_mfma_f32_16x16x32_bf16(aL[rf], bH[cf], ACC[rf][cf], 0, 0, 0); \
  }

__global__ __launch_bounds__(256, 2) void gcn_gru_fused(
    const float* __restrict__ Hp, float* __restrict__ Hn,
    const int* __restrict__ csr_src, const float* __restrict__ csr_w,
    const int* __restrict__ rowptr,
    const ushort* __restrict__ Bhi, const ushort* __restrict__ Blo,
    const float* __restrict__ bih, const float* __restrict__ bhh) {
  __shared__ ushort AsH[8192];
  __shared__ ushort AsL[8192];
  __shared__ ushort HsH[8192];
  __shared__ ushort HsL[8192];
  const int tid = threadIdx.x;
  const int tile = blockIdx.x;
  const long rowbase = (long)tile * 64;

  const int local = tid >> 2;   // 0..63
  const int kc4 = tid & 3;      // dim block: d = kc4*32 + 0..31
  const int rf0 = local >> 4, c16l = local & 15;
  const int lwr = kc4 * 2048 + rf0 * 512 + c16l * 8;

  // ---- Phase 0: stage own rows ----
  {
    const float* p = Hp + (size_t)(rowbase + local) * Hh + kc4 * 32;
#pragma unroll
    for (int g2 = 0; g2 < 4; ++g2) {
      f32x4 v0 = *(const f32x4*)(p + g2 * 8);
      f32x4 v1 = *(const f32x4*)(p + g2 * 8 + 4);
      u16x8 vh, vl;
#pragma unroll
      for (int m = 0; m < 4; ++m) {
        ushort hb0 = f2bf(v0[m]);
        vh[m] = hb0;
        vl[m] = f2bf(v0[m] - bf2f(hb0));
        ushort hb1 = f2bf(v1[m]);
        vh[4 + m] = hb1;
        vl[4 + m] = f2bf(v1[m] - bf2f(hb1));
      }
      *(u16x8*)(HsH + lwr + g2 * 128) = vh;
      *(u16x8*)(HsL + lwr + g2 * 128) = vl;
    }
  }

  // ---- Phase 1: gather ----
  {
    const long node = rowbase + local;
    float acc[32];
#pragma unroll
    for (int m = 0; m < 32; ++m) acc[m] = 0.0f;
    if (node < Nn) {
      const int e0 = rowptr[node], e1 = rowptr[node + 1];
      for (int e = e0; e < e1; ++e) {
        const int src = csr_src[e];
        const float w = csr_w[e];
        const float* p = Hp + (size_t)src * Hh + kc4 * 32;
#pragma unroll
        for (int g2 = 0; g2 < 4; ++g2) {
          f32x4 v0 = *(const f32x4*)(p + g2 * 8);
          f32x4 v1 = *(const f32x4*)(p + g2 * 8 + 4);
#pragma unroll
          for (int m = 0; m < 4; ++m) {
            acc[g2 * 8 + m] = fmaf(w, v0[m], acc[g2 * 8 + m]);
            acc[g2 * 8 + 4 + m] = fmaf(w, v1[m], acc[g2 * 8 + 4 + m]);
          }
        }
      }
    }
#pragma unroll
    for (int g2 = 0; g2 < 4; ++g2) {
      u16x8 vh, vl;
#pragma unroll
      for (int j = 0; j < 8; ++j) {
        float v = acc[g2 * 8 + j];
        ushort hb = f2bf(v);
        vh[j] = hb;
        vl[j] = f2bf(v - bf2f(hb));
      }
      *(u16x8*)(AsH + lwr + g2 * 128) = vh;
      *(u16x8*)(AsL + lwr + g2 * 128) = vl;
    }
  }
  __syncthreads();

  // ---- Phase 2: MFMA ----
  const int wave = tid >> 6, lane = tid & 63;
  const int g = lane >> 4, c16 = lane & 15;
  const int lbase = g * 128 + c16 * 8;

  f32x4 accR[4][2], accZ[4][2], accXN[4][2], accHN[4][2];
#pragma unroll
  for (int rf = 0; rf < 4; ++rf)
#pragma unroll
    for (int cf = 0; cf < 2; ++cf) {
      accR[rf][cf] = (f32x4){0.f, 0.f, 0.f, 0.f};
      accZ[rf][cf] = (f32x4){0.f, 0.f, 0.f, 0.f};
      accXN[rf][cf] = (f32x4){0.f, 0.f, 0.f, 0.f};
      accHN[rf][cf] = (f32x4){0.f, 0.f, 0.f, 0.f};
    }

#pragma unroll
  for (int kc = 0; kc < 4; ++kc) {
    bf16x8 aH[4], aL[4];
#pragma unroll
    for (int rf = 0; rf < 4; ++rf) {
      int off = kc * 2048 + rf * 512 + lbase;
      aH[rf] = *(const bf16x8*)(AsH + off);
      aL[rf] = *(const bf16x8*)(AsL + off);
    }
    DO_GATE(0, accR)
    DO_GATE(1, accZ)
    DO_GATE(2, accXN)
  }
#pragma unroll
  for (int kc = 4; kc < 8; ++kc) {
    bf16x8 aH[4], aL[4];
#pragma unroll
    for (int rf = 0; rf < 4; ++rf) {
      int off = (kc - 4) * 2048 + rf * 512 + lbase;
      aH[rf] = *(const bf16x8*)(HsH + off);
      aL[rf] = *(const bf16x8*)(HsL + off);
    }
    DO_GATE(0, accR)
    DO_GATE(1, accZ)
    DO_GATE(2, accHN)
  }

  // ---- Phase 3: epilogue ----
#pragma unroll
  for (int cf = 0; cf < 2; ++cf) {
    const int c = (wave * 2 + cf) * 16 + c16;
    const float br = bih[c] + bhh[c];
    const float bz = bih[128 + c] + bhh[128 + c];
    const float bxn = bih[256 + c];
    const float bhn = bhh[256 + c];
    const int hcol = (cf * 2 + (c16 >> 3)) * 128 + (c16 & 7);
#pragma unroll
    for (int rf = 0; rf < 4; ++rf) {
#pragma unroll
      for (int reg = 0; reg < 4; ++reg) {
        const int lr = g * 4 + reg;  // local row within 16-block
        const int hoff = wave * 2048 + rf * 512 + hcol + lr * 8;
        float hold = bf2f(HsH[hoff]) + bf2f(HsL[hoff]);
        float rr = sigmoidf_(accR[rf][cf][reg] + br);
        float zz = sigmoidf_(accZ[rf][cf][reg] + bz);
        float nn = tanh_fast(accXN[rf][cf][reg] + bxn + rr * (accHN[rf][cf][reg] + bhn));
        Hn[(size_t)(rowbase + rf * 16 + lr) * Hh + c] = (1.0f - zz) * nn + zz * hold;
      }
    }
  }
}

// ---- Fused max(h1..h5) + MLP ----
// Block = 64 nodes, 4 waves; wave w owns cols [16w, 16w+16) of hid (64 cols).
__global__ __launch_bounds__(256, 2) void mlp_max_mfma(
    const float* __restrict__ H1, const float* __restrict__ H2,
    const float* __restrict__ H3, const float* __restrict__ H4,
    const float* __restrict__ H5,
    const ushort* __restrict__ Bh, const ushort* __restrict__ Bl,
    const float* __restrict__ bm1, const float* __restrict__ Wm2,
    const float* __restrict__ bm2, float* __restrict__ out) {
  __shared__ float red[4][64];
  const int tid = threadIdx.x;
  const int wave = tid >> 6, lane = tid & 63;
  const int g = lane >> 4, c16 = lane & 15;
  const long rowbase = (long)blockIdx.x * 64;

  f32x4 acc[4];
#pragma unroll
  for (int rf = 0; rf < 4; ++rf) acc[rf] = (f32x4){0.f, 0.f, 0.f, 0.f};

#pragma unroll
  for (int kc = 0; kc < 4; ++kc) {
    bf16x8 aH[4], aL[4];
#pragma unroll
    for (int rf = 0; rf < 4; ++rf) {
      size_t o = (size_t)(rowbase + rf * 16 + c16) * Hh + kc * 32 + g * 8;
      f32x4 m0 = *(const f32x4*)(H1 + o);
      f32x4 m1 = *(const f32x4*)(H1 + o + 4);
      m0 = max4(m0, *(const f32x4*)(H2 + o));
      m1 = max4(m1, *(const f32x4*)(H2 + o + 4));
      m0 = max4(m0, *(const f32x4*)(H3 + o));
      m1 = max4(m1, *(const f32x4*)(H3 + o + 4));
      m0 = max4(m0, *(const f32x4*)(H4 + o));
      m1 = max4(m1, *(const f32x4*)(H4 + o + 4));
      m0 = max4(m0, *(const f32x4*)(H5 + o));
      m1 = max4(m1, *(const f32x4*)(H5 + o + 4));
      u16x8 vh, vl;
#pragma unroll
      for (int m = 0; m < 4; ++m) {
        ushort hb0 = f2bf(m0[m]);
        vh[m] = hb0;
        vl[m] = f2bf(m0[m] - bf2f(hb0));
        ushort hb1 = f2bf(m1[m]);
        vh[4 + m] = hb1;
        vl[4 + m] = f2bf(m1[m] - bf2f(hb1));
      }
      aH[rf] = (bf16x8)vh;
      aL[rf] = (bf16x8)vl;
    }
    size_t boff = (((size_t)(kc * 4 + wave) * 4 + g) * 16 + c16) * 8;
    bf16x8 bH = *(const bf16x8*)(Bh + boff);
    bf16x8 bL = *(const bf16x8*)(Bl + boff);
#pragma unroll
    for (int rf = 0; rf < 4; ++rf)
      acc[rf] = __builtin_amdgcn_mfma_f32_16x16x32_bf16(aH[rf], bH, acc[rf], 0, 0, 0);
#pragma unroll
    for (int rf = 0; rf < 4; ++rf)
      acc[rf] = __builtin_amdgcn_mfma_f32_16x16x32_bf16(aH[rf], bL, acc[rf], 0, 0, 0);
#pragma unroll
    for (int rf = 0; rf < 4; ++rf)
      acc[rf] = __builtin_amdgcn_mfma_f32_16x16x32_bf16(aL[rf], bH, acc[rf], 0, 0, 0);
  }

  const int c = wave * 16 + c16;
  const float b1 = bm1[c];
  const float w2 = Wm2[c];
#pragma unroll
  for (int rf = 0; rf < 4; ++rf) {
#pragma unroll
    for (int reg = 0; reg < 4; ++reg) {
      float v = acc[rf][reg] + b1;
      v = v > 0.f ? v : 0.01f * v;
      v *= w2;
#pragma unroll
      for (int off = 1; off < 16; off <<= 1) v += __shfl_xor(v, off);
      if (c16 == 0) red[wave][rf * 16 + g * 4 + reg] = v;
    }
  }
  __syncthreads();
  if (tid < 64) {
    long row = rowbase + tid;
    if (row < Nn)
      out[row] = red[0][tid] + red[1][tid] + red[2][tid] + red[3][tid] + bm2[0];
  }
}

extern "C" void kernel_launch(void* const* d_in, const int* in_sizes, int n_in,
                              void* d_out, int out_size, void* d_ws, size_t ws_size,
                              hipStream_t stream) {
  const float* X = (const float*)d_in[0];
  const int* ei = (const int*)d_in[1];
  const float* W0 = (const float*)d_in[2];
  const float* b0 = (const float*)d_in[3];
  const float* Wih = (const float*)d_in[4];
  const float* Whh = (const float*)d_in[5];
  const float* bih = (const float*)d_in[6];
  const float* bhh = (const float*)d_in[7];
  const float* Wm1 = (const float*)d_in[8];
  const float* bm1 = (const float*)d_in[9];
  const float* Wm2 = (const float*)d_in[10];
  const float* bm2 = (const float*)d_in[11];
  float* out = (float*)d_out;

  char* ws = (char*)d_ws;
  size_t off = 0;
  auto alloc = [&](size_t bytes) -> void* {
    void* p = ws + off;
    off = (off + bytes + 255) & ~(size_t)255;
    return p;
  };
  float* Hs[5];
  for (int i = 0; i < 5; ++i) Hs[i] = (float*)alloc((size_t)NP * Hh * 4);
  ushort* Bhi = (ushort*)alloc((size_t)8 * 24 * 4 * 16 * 8 * 2);
  ushort* Blo = (ushort*)alloc((size_t)8 * 24 * 4 * 16 * 8 * 2);
  ushort* Bmh = (ushort*)alloc((size_t)1024 * 8 * 2);
  ushort* Bml = (ushort*)alloc((size_t)1024 * 8 * 2);
  float* dis = (float*)alloc((size_t)Nn * 4);
  int* degi = (int*)alloc((size_t)Nn * 4);
  int* cnt = (int*)alloc((size_t)Nn * 4);
  int* rowptr = (int*)alloc((size_t)(Nn + 1) * 4);
  int* cursor = (int*)alloc((size_t)Nn * 4);
  int* bsum = (int*)alloc(512 * 4);
  int* bpre = (int*)alloc(512 * 4);
  int* csr_src = (int*)alloc((size_t)Ee * 4);
  float* csr_w = (float*)alloc((size_t)Ee * 4);
  (void)ws_size;
  (void)in_sizes;
  (void)n_in;
  (void)out_size;

  const int NB = (Nn + 255) / 256;  // 391
  const int EB = (Ee + 255) / 256;  // 2344

  zero_kernel<<<NB, 256, 0, stream>>>(degi, cnt, Nn);
  count_kernel<<<EB, 256, 0, stream>>>(ei, degi, cnt);
  dis_kernel<<<NB, 256, 0, stream>>>(degi, dis);
  scan_partial<<<NB, 256, 0, stream>>>(cnt, bsum);
  scan_bsums<<<1, 512, 0, stream>>>(bsum, bpre, NB);
  scan_final<<<NB, 256, 0, stream>>>(cnt, bpre, rowptr, cursor);
  fill_kernel<<<EB, 256, 0, stream>>>(ei, dis, cursor, csr_src, csr_w);
  pack_kernel<<<48, 256, 0, stream>>>(Wih, Whh, Bhi, Blo);
  pack_mlp<<<4, 256, 0, stream>>>(Wm1, Bmh, Bml);
  h0_kernel<<<(NP * Hh) / 256, 256, 0, stream>>>(X, W0, b0, Hs[0]);

  // iteration t: read Hs[(t-1)%5], write Hs[t%5]  (t=5 reuses slot 0; h0 is dead by then)
  for (int t = 1; t <= 5; ++t) {
    gcn_gru_fused<<<NT, 256, 0, stream>>>(Hs[(t - 1) % 5], Hs[t % 5], csr_src, csr_w,
                                          rowptr, Bhi, Blo, bih, bhh);
  }

  mlp_max_mfma<<<NT, 256, 0, stream>>>(Hs[1], Hs[2], Hs[3], Hs[4], Hs[0], Bmh, Bml,
                                       bm1, Wm2, bm2, out);
}